// Round 2
// baseline (722.294 us; speedup 1.0000x reference)
//
#include <hip/hip_runtime.h>
#include <math.h>

#define BATCH 8
#define NMEL 128
#define TT 2048
#define LL 1048576          // TT * 512
#define NCHUNK 128
#define CHUNK 8192          // LL / NCHUNK

static constexpr double RATIO = 2047.0 / 1048575.0;   // (T-1)/(L-1)
static constexpr double INV_SR = 1.0 / 44100.0;

// f0 linear upsample at sample n (align_corners=True semantics, f64 pos, f32 blend)
__device__ __forceinline__ float f0_at(const float* __restrict__ row, int n) {
    double pos = (double)n * RATIO;
    double fp = floor(pos);
    int i0 = (int)fp;
    int i1 = i0 + 1; if (i1 > TT - 1) i1 = TT - 1;
    float w = (float)(pos - fp);
    return row[i0] * (1.0f - w) + row[i1] * w;
}

// ---------------- conv layers 1 & 2 (128 -> 128, leaky relu 0.2) ----------------
// block = 256 threads, each block does one (batch, 64-wide t tile).
// thread: 1 t position (tid&63), 32 output channels ((tid>>6)*32 .. +31)
template<int K>
__global__ __launch_bounds__(256) void conv_kernel(
    const float* __restrict__ in,   // [B][128][T]
    const float* __restrict__ wgt,  // [128][128][K]
    const float* __restrict__ bias, // [128]
    float* __restrict__ out)        // [B][128][T]
{
    constexpr int PAD = K / 2;
    constexpr int TW = 64 + K - 1;
    __shared__ float tile[NMEL][TW];
    int b = blockIdx.x >> 5;          // 32 tiles per batch (2048/64)
    int t0 = (blockIdx.x & 31) * 64;
    int tid = threadIdx.x;
    const float* inb = in + (size_t)b * NMEL * TT;

    for (int idx = tid; idx < NMEL * TW; idx += 256) {
        int ch = idx / TW;
        int x  = idx - ch * TW;
        int t  = t0 - PAD + x;
        tile[ch][x] = (t >= 0 && t < TT) ? inb[ch * TT + t] : 0.0f;
    }
    __syncthreads();

    int tl = tid & 63;
    int cobase = (tid >> 6) * 32;
    cobase = __builtin_amdgcn_readfirstlane(cobase);  // wave-uniform -> scalar weight loads

    float acc[32];
    #pragma unroll
    for (int j = 0; j < 32; ++j) acc[j] = bias[cobase + j];

    for (int ci = 0; ci < NMEL; ++ci) {
        float xv[K];
        #pragma unroll
        for (int k = 0; k < K; ++k) xv[k] = tile[ci][tl + k];
        const float* wrow = wgt + ((size_t)cobase * NMEL + ci) * K;
        #pragma unroll
        for (int j = 0; j < 32; ++j) {
            #pragma unroll
            for (int k = 0; k < K; ++k)
                acc[j] = fmaf(wrow[(size_t)j * NMEL * K + k], xv[k], acc[j]);
        }
    }

    float* outb = out + ((size_t)b * NMEL + cobase) * TT + t0 + tl;
    #pragma unroll
    for (int j = 0; j < 32; ++j) {
        float v = acc[j];
        v = v > 0.0f ? v : 0.2f * v;
        outb[(size_t)j * TT] = v;
    }
}

// ---------------- conv layer 3 (128 -> 2, clip [0,1]) ----------------
__global__ __launch_bounds__(256) void conv3_kernel(
    const float* __restrict__ in,  // [B][128][T]
    const float* __restrict__ w3,  // [2][128][3]
    const float* __restrict__ b3,  // [2]
    float* __restrict__ mags)      // [B][2][T]
{
    int gid = blockIdx.x * 256 + threadIdx.x;  // over B*T
    int b = gid >> 11;
    int t = gid & (TT - 1);
    const float* inb = in + (size_t)b * NMEL * TT;
    float a0 = b3[0], a1 = b3[1];
    for (int ci = 0; ci < NMEL; ++ci) {
        #pragma unroll
        for (int k = 0; k < 3; ++k) {
            int t2 = t + k - 1;
            float x = (t2 >= 0 && t2 < TT) ? inb[ci * TT + t2] : 0.0f;
            a0 = fmaf(w3[ci * 3 + k], x, a0);
            a1 = fmaf(w3[384 + ci * 3 + k], x, a1);
        }
    }
    a0 = fminf(fmaxf(a0, 0.0f), 1.0f);
    a1 = fminf(fmaxf(a1, 0.0f), 1.0f);
    mags[(size_t)b * 2 * TT + t]      = a0;
    mags[((size_t)b * 2 + 1) * TT + t] = a1;
}

// ---------------- phase scan level 1: per-chunk f64 sums ----------------
__global__ __launch_bounds__(256) void chunksum_kernel(
    const float* __restrict__ f0f, double* __restrict__ sums)
{
    int b = blockIdx.x >> 7;
    int c = blockIdx.x & (NCHUNK - 1);
    const float* row = f0f + b * TT;
    int tid = threadIdx.x;
    int start = c * CHUNK + tid * 32;
    double s = 0.0;
    #pragma unroll
    for (int i = 0; i < 32; ++i)
        s += (double)f0_at(row, start + i) * INV_SR;
    __shared__ double red[256];
    red[tid] = s;
    __syncthreads();
    for (int off = 128; off > 0; off >>= 1) {
        if (tid < off) red[tid] += red[tid + off];
        __syncthreads();
    }
    if (tid == 0) sums[blockIdx.x] = red[0];
}

// ---------------- phase scan level 2: per-batch serial scan of 128 chunks ----------------
__global__ void scanoff_kernel(const double* __restrict__ sums, double* __restrict__ offs)
{
    int b = threadIdx.x;
    if (b < BATCH) {
        double run = 0.0;
        for (int c = 0; c < NCHUNK; ++c) {
            offs[b * NCHUNK + c] = run;
            run += sums[b * NCHUNK + c];
        }
    }
}

// ---------------- final fused kernel ----------------
__device__ __forceinline__ int swz(int idx) { return idx ^ ((idx >> 5) & 31); }

__global__ __launch_bounds__(256) void final_kernel(
    const float* __restrict__ f0f,
    const float* __restrict__ noise,
    const float* __restrict__ mags,
    const double* __restrict__ offs,
    float* __restrict__ out)
{
    int b = blockIdx.x >> 7;
    int c = blockIdx.x & (NCHUNK - 1);
    const float* row = f0f + b * TT;
    int tid = threadIdx.x;
    __shared__ float fracs[CHUNK];
    __shared__ double red[256];

    int chunkBase = c * CHUNK;
    int start = chunkBase + tid * 32;

    float f0v[32];
    double s = 0.0;
    #pragma unroll
    for (int i = 0; i < 32; ++i) {
        f0v[i] = f0_at(row, start + i);
        s += (double)f0v[i] * INV_SR;
    }
    red[tid] = s;
    __syncthreads();
    // Hillis-Steele inclusive scan over 256 thread sums
    for (int off = 1; off < 256; off <<= 1) {
        double v = (tid >= off) ? red[tid - off] : 0.0;
        __syncthreads();
        red[tid] += v;
        __syncthreads();
    }
    double run = offs[b * NCHUNK + c] + red[tid] - s;  // exclusive prefix for this thread

    #pragma unroll
    for (int i = 0; i < 32; ++i) {
        run += (double)f0v[i] * INV_SR;
        double fr = run - rint(run);               // phase - round(phase), half-to-even
        fracs[swz(tid * 32 + i)] = (float)fr;      // swizzled: conflict-free write & read
    }
    __syncthreads();

    const size_t BL = (size_t)BATCH * LL;
    const size_t outBase = (size_t)b * LL;
    const float* m0row = mags + (size_t)b * 2 * TT;
    const float* m1row = m0row + TT;

    #pragma unroll 4
    for (int i = 0; i < 32; ++i) {
        int idx = i * 256 + tid;                   // coalesced across lanes
        int n = chunkBase + idx;
        double pos = (double)n * RATIO;
        double fp = floor(pos);
        int i0 = (int)fp;
        int i1 = i0 + 1; if (i1 > TT - 1) i1 = TT - 1;
        float w = (float)(pos - fp);
        float f0 = row[i0] * (1.0f - w) + row[i1] * w;
        float m0 = m0row[i0] * (1.0f - w) + m0row[i1] * w;
        float m1 = m1row[i0] * (1.0f - w) + m1row[i1] * w;
        float ph = fracs[swz(idx)];
        float x = 44100.0f * ph / (f0 + 1e-8f);
        float px = 3.14159265358979323f * x;
        float comb = (x == 0.0f) ? 1.0f : (sinf(px) / px);
        float nz = noise[outBase + n];
        float ns = fminf(fmaxf(nz * m0, -1.0f), 1.0f);
        float cs = fminf(fmaxf(comb * m1, -1.0f), 1.0f);
        float sig = fminf(fmaxf(ns + cs, -1.0f), 1.0f);
        out[outBase + n]          = sig;
        out[BL + outBase + n]     = cs;
        out[2 * BL + outBase + n] = ns;
    }
}

extern "C" void kernel_launch(void* const* d_in, const int* in_sizes, int n_in,
                              void* d_out, int out_size, void* d_ws, size_t ws_size,
                              hipStream_t stream) {
    const float* mel   = (const float*)d_in[0];  // [8,128,2048]
    const float* f0f   = (const float*)d_in[1];  // [8,2048]
    const float* noise = (const float*)d_in[2];  // [8,1048576]
    const float* w1    = (const float*)d_in[3];  // [128,128,7]
    const float* b1    = (const float*)d_in[4];
    const float* w2    = (const float*)d_in[5];  // [128,128,3]
    const float* b2    = (const float*)d_in[6];
    const float* w3    = (const float*)d_in[7];  // [2,128,3]
    const float* b3    = (const float*)d_in[8];
    float* out = (float*)d_out;

    // workspace layout
    float* h1   = (float*)d_ws;                                  // 8 MB
    float* h2   = h1 + (size_t)BATCH * NMEL * TT;                // 8 MB
    float* mags = h2 + (size_t)BATCH * NMEL * TT;                // 128 KB
    double* sums = (double*)(mags + (size_t)BATCH * 2 * TT);     // 8 KB (8-byte aligned)
    double* offs = sums + BATCH * NCHUNK;                        // 8 KB

    conv_kernel<7><<<BATCH * 32, 256, 0, stream>>>(mel, w1, b1, h1);
    conv_kernel<3><<<BATCH * 32, 256, 0, stream>>>(h1, w2, b2, h2);
    conv3_kernel<<<(BATCH * TT) / 256, 256, 0, stream>>>(h2, w3, b3, mags);
    chunksum_kernel<<<BATCH * NCHUNK, 256, 0, stream>>>(f0f, sums);
    scanoff_kernel<<<1, 64, 0, stream>>>(sums, offs);
    final_kernel<<<BATCH * NCHUNK, 256, 0, stream>>>(f0f, noise, mags, offs, out);
}

// Round 3
// 305.563 us; speedup vs baseline: 2.3638x; 2.3638x over previous
//
#include <hip/hip_runtime.h>
#include <math.h>

#define BATCH 8
#define NMEL 128
#define TT 2048
#define LL 1048576          // TT * 512
#define NCHUNK 128
#define CHUNK 8192          // LL / NCHUNK

static constexpr double RATIO = 2047.0 / 1048575.0;   // (T-1)/(L-1)
static constexpr double INV_SR = 1.0 / 44100.0;

// f0 linear upsample at sample n (align_corners=True semantics, f64 pos, f32 blend)
__device__ __forceinline__ float f0_at(const float* __restrict__ row, int n) {
    double pos = (double)n * RATIO;
    double fp = floor(pos);
    int i0 = (int)fp;
    int i1 = i0 + 1; if (i1 > TT - 1) i1 = TT - 1;
    float w = (float)(pos - fp);
    return row[i0] * (1.0f - w) + row[i1] * w;
}

// ---------------- conv layers 1 & 2 as LDS-tiled register-blocked GEMM ----------------
// out[co][t] = bias[co] + sum_{ci,k} w[co][ci][k] * in[ci][t+k-PAD], then leaky-relu 0.2
// Block: 256 thr, tile 64co x 64t, thread 4co x 4t. Grid: 8B x 2cog x 32ttile = 512.
template<int K>
__global__ __launch_bounds__(256) void conv_gemm(
    const float* __restrict__ in,   // [B][128][T]
    const float* __restrict__ wgt,  // [128][128][K]
    const float* __restrict__ bias, // [128]
    float* __restrict__ out)        // [B][128][T]
{
    constexpr int PAD = K / 2;
    constexpr int TW  = 64 + K - 1;           // staged t width
    constexpr int TWP = (TW + 3) & ~3;        // padded stride (b128-aligned rows)
    constexpr int CC  = 16;                   // ci chunk
    constexpr int CHW = CC * K;               // weight words per co per chunk
    constexpr int NCH = NMEL / CC;            // 8 chunks
    constexpr int WPT = CHW / 4;              // weight words per thread (28 / 12)

    __shared__ float Xs[CC][TWP];
    __shared__ float Ws[CHW][64];             // [ci*K+k][co] (transposed for b128 reads)

    int blk  = blockIdx.x;
    int b    = blk >> 6;
    int cog  = (blk >> 5) & 1;
    int t0   = (blk & 31) * 64;
    int cobase = cog * 64;
    int tid  = threadIdx.x;
    int tco  = tid >> 4;                      // 0..15 -> co = cobase + tco*4 ..+3
    int tt   = tid & 15;                      // 0..15 -> t  = t0 + tt*4 ..+3

    const float* inb = in + (size_t)b * NMEL * TT;

    float acc[4][4];
    #pragma unroll
    for (int j = 0; j < 4; ++j) {
        float bj = bias[cobase + tco * 4 + j];
        #pragma unroll
        for (int i = 0; i < 4; ++i) acc[j][i] = bj;
    }

    int wco = tid >> 2;                       // 0..63: co this thread stages
    int wp  = tid & 3;                        // quarter of the chunk row

    for (int ch = 0; ch < NCH; ++ch) {
        // ---- stage X chunk [16 ci][TW t] ----
        for (int idx = tid; idx < CC * TW; idx += 256) {
            int cc = idx / TW;
            int x  = idx - cc * TW;
            int t  = t0 - PAD + x;
            Xs[cc][x] = (t >= 0 && t < TT) ? inb[(ch * CC + cc) * TT + t] : 0.0f;
        }
        // ---- stage W chunk, transposed ----
        {
            const float* wsrc = wgt + ((size_t)(cobase + wco) * NMEL + ch * CC) * K + wp * WPT;
            float tmp[WPT];
            #pragma unroll
            for (int v = 0; v < WPT / 4; ++v) {
                float4 q = ((const float4*)wsrc)[v];
                tmp[v*4+0] = q.x; tmp[v*4+1] = q.y; tmp[v*4+2] = q.z; tmp[v*4+3] = q.w;
            }
            #pragma unroll
            for (int v = 0; v < WPT; ++v)
                Ws[wp * WPT + v][wco] = tmp[v];
        }
        __syncthreads();

        // ---- compute ----
        #pragma unroll
        for (int cc = 0; cc < CC; ++cc) {
            float xv[4 + K - 1];
            #pragma unroll
            for (int i = 0; i < 4 + K - 1; ++i) xv[i] = Xs[cc][tt * 4 + i];
            #pragma unroll
            for (int k = 0; k < K; ++k) {
                float4 wq = *(const float4*)&Ws[cc * K + k][tco * 4];
                float wv[4] = {wq.x, wq.y, wq.z, wq.w};
                #pragma unroll
                for (int j = 0; j < 4; ++j)
                    #pragma unroll
                    for (int i = 0; i < 4; ++i)
                        acc[j][i] = fmaf(wv[j], xv[i + k], acc[j][i]);
            }
        }
        __syncthreads();
    }

    // ---- epilogue: leaky relu + float4 stores ----
    float* outb = out + ((size_t)b * NMEL + cobase + tco * 4) * TT + t0 + tt * 4;
    #pragma unroll
    for (int j = 0; j < 4; ++j) {
        float4 r;
        float v0 = acc[j][0], v1 = acc[j][1], v2 = acc[j][2], v3 = acc[j][3];
        r.x = v0 > 0.0f ? v0 : 0.2f * v0;
        r.y = v1 > 0.0f ? v1 : 0.2f * v1;
        r.z = v2 > 0.0f ? v2 : 0.2f * v2;
        r.w = v3 > 0.0f ? v3 : 0.2f * v3;
        *(float4*)(outb + (size_t)j * TT) = r;
    }
}

// ---------------- conv layer 3 (128 -> 2, clip [0,1]) ----------------
__global__ __launch_bounds__(256) void conv3_kernel(
    const float* __restrict__ in,  // [B][128][T]
    const float* __restrict__ w3,  // [2][128][3]
    const float* __restrict__ b3,  // [2]
    float* __restrict__ mags)      // [B][2][T]
{
    int gid = blockIdx.x * 256 + threadIdx.x;  // over B*T
    int b = gid >> 11;
    int t = gid & (TT - 1);
    const float* inb = in + (size_t)b * NMEL * TT;
    float a0 = b3[0], a1 = b3[1];
    for (int ci = 0; ci < NMEL; ++ci) {
        #pragma unroll
        for (int k = 0; k < 3; ++k) {
            int t2 = t + k - 1;
            float x = (t2 >= 0 && t2 < TT) ? inb[ci * TT + t2] : 0.0f;
            a0 = fmaf(w3[ci * 3 + k], x, a0);
            a1 = fmaf(w3[384 + ci * 3 + k], x, a1);
        }
    }
    a0 = fminf(fmaxf(a0, 0.0f), 1.0f);
    a1 = fminf(fmaxf(a1, 0.0f), 1.0f);
    mags[(size_t)b * 2 * TT + t]      = a0;
    mags[((size_t)b * 2 + 1) * TT + t] = a1;
}

// ---------------- phase scan level 1: per-chunk f64 sums ----------------
__global__ __launch_bounds__(256) void chunksum_kernel(
    const float* __restrict__ f0f, double* __restrict__ sums)
{
    int b = blockIdx.x >> 7;
    int c = blockIdx.x & (NCHUNK - 1);
    const float* row = f0f + b * TT;
    int tid = threadIdx.x;
    int start = c * CHUNK + tid * 32;
    double s = 0.0;
    #pragma unroll
    for (int i = 0; i < 32; ++i)
        s += (double)f0_at(row, start + i) * INV_SR;
    __shared__ double red[256];
    red[tid] = s;
    __syncthreads();
    for (int off = 128; off > 0; off >>= 1) {
        if (tid < off) red[tid] += red[tid + off];
        __syncthreads();
    }
    if (tid == 0) sums[blockIdx.x] = red[0];
}

// ---------------- phase scan level 2: per-batch serial scan of 128 chunks ----------------
__global__ void scanoff_kernel(const double* __restrict__ sums, double* __restrict__ offs)
{
    int b = threadIdx.x;
    if (b < BATCH) {
        double run = 0.0;
        for (int c = 0; c < NCHUNK; ++c) {
            offs[b * NCHUNK + c] = run;
            run += sums[b * NCHUNK + c];
        }
    }
}

// ---------------- final fused kernel ----------------
__device__ __forceinline__ int swz(int idx) { return idx ^ ((idx >> 5) & 31); }

__global__ __launch_bounds__(256) void final_kernel(
    const float* __restrict__ f0f,
    const float* __restrict__ noise,
    const float* __restrict__ mags,
    const double* __restrict__ offs,
    float* __restrict__ out)
{
    int b = blockIdx.x >> 7;
    int c = blockIdx.x & (NCHUNK - 1);
    const float* row = f0f + b * TT;
    int tid = threadIdx.x;
    __shared__ float fracs[CHUNK];
    __shared__ double red[256];

    int chunkBase = c * CHUNK;
    int start = chunkBase + tid * 32;

    float f0v[32];
    double s = 0.0;
    #pragma unroll
    for (int i = 0; i < 32; ++i) {
        f0v[i] = f0_at(row, start + i);
        s += (double)f0v[i] * INV_SR;
    }
    red[tid] = s;
    __syncthreads();
    // Hillis-Steele inclusive scan over 256 thread sums
    for (int off = 1; off < 256; off <<= 1) {
        double v = (tid >= off) ? red[tid - off] : 0.0;
        __syncthreads();
        red[tid] += v;
        __syncthreads();
    }
    double run = offs[b * NCHUNK + c] + red[tid] - s;  // exclusive prefix for this thread

    #pragma unroll
    for (int i = 0; i < 32; ++i) {
        run += (double)f0v[i] * INV_SR;
        double fr = run - rint(run);               // phase - round(phase), half-to-even
        fracs[swz(tid * 32 + i)] = (float)fr;      // swizzled: conflict-free write & read
    }
    __syncthreads();

    const size_t BL = (size_t)BATCH * LL;
    const size_t outBase = (size_t)b * LL;
    const float* m0row = mags + (size_t)b * 2 * TT;
    const float* m1row = m0row + TT;

    #pragma unroll 4
    for (int i = 0; i < 32; ++i) {
        int idx = i * 256 + tid;                   // coalesced across lanes
        int n = chunkBase + idx;
        double pos = (double)n * RATIO;
        double fp = floor(pos);
        int i0 = (int)fp;
        int i1 = i0 + 1; if (i1 > TT - 1) i1 = TT - 1;
        float w = (float)(pos - fp);
        float f0 = row[i0] * (1.0f - w) + row[i1] * w;
        float m0 = m0row[i0] * (1.0f - w) + m0row[i1] * w;
        float m1 = m1row[i0] * (1.0f - w) + m1row[i1] * w;
        float ph = fracs[swz(idx)];
        float x = 44100.0f * ph / (f0 + 1e-8f);
        float px = 3.14159265358979323f * x;
        float comb = (x == 0.0f) ? 1.0f : (sinf(px) / px);
        float nz = noise[outBase + n];
        float ns = fminf(fmaxf(nz * m0, -1.0f), 1.0f);
        float cs = fminf(fmaxf(comb * m1, -1.0f), 1.0f);
        float sig = fminf(fmaxf(ns + cs, -1.0f), 1.0f);
        out[outBase + n]          = sig;
        out[BL + outBase + n]     = cs;
        out[2 * BL + outBase + n] = ns;
    }
}

extern "C" void kernel_launch(void* const* d_in, const int* in_sizes, int n_in,
                              void* d_out, int out_size, void* d_ws, size_t ws_size,
                              hipStream_t stream) {
    const float* mel   = (const float*)d_in[0];  // [8,128,2048]
    const float* f0f   = (const float*)d_in[1];  // [8,2048]
    const float* noise = (const float*)d_in[2];  // [8,1048576]
    const float* w1    = (const float*)d_in[3];  // [128,128,7]
    const float* b1    = (const float*)d_in[4];
    const float* w2    = (const float*)d_in[5];  // [128,128,3]
    const float* b2    = (const float*)d_in[6];
    const float* w3    = (const float*)d_in[7];  // [2,128,3]
    const float* b3    = (const float*)d_in[8];
    float* out = (float*)d_out;

    // workspace layout
    float* h1   = (float*)d_ws;                                  // 8 MB
    float* h2   = h1 + (size_t)BATCH * NMEL * TT;                // 8 MB
    float* mags = h2 + (size_t)BATCH * NMEL * TT;                // 128 KB
    double* sums = (double*)(mags + (size_t)BATCH * 2 * TT);     // 8 KB (8-byte aligned)
    double* offs = sums + BATCH * NCHUNK;                        // 8 KB

    conv_gemm<7><<<BATCH * 64, 256, 0, stream>>>(mel, w1, b1, h1);
    conv_gemm<3><<<BATCH * 64, 256, 0, stream>>>(h1, w2, b2, h2);
    conv3_kernel<<<(BATCH * TT) / 256, 256, 0, stream>>>(h2, w3, b3, mags);
    chunksum_kernel<<<BATCH * NCHUNK, 256, 0, stream>>>(f0f, sums);
    scanoff_kernel<<<1, 64, 0, stream>>>(sums, offs);
    final_kernel<<<BATCH * NCHUNK, 256, 0, stream>>>(f0f, noise, mags, offs, out);
}

// Round 4
// 289.312 us; speedup vs baseline: 2.4966x; 1.0562x over previous
//
#include <hip/hip_runtime.h>
#include <math.h>

#define BATCH 8
#define NMEL 128
#define TT 2048
#define LL 1048576          // TT * 512
#define NCHUNK 128
#define CHUNK 8192          // LL / NCHUNK

static constexpr double RATIO = 2047.0 / 1048575.0;   // (T-1)/(L-1)
static constexpr double INV_SR = 1.0 / 44100.0;

// Ws row-XOR swizzle in 16B units: rows that collide on a bank land in
// distinct 4-float bank groups (verified for row deltas 28 (K=7) and 12 (K=3)).
__device__ __host__ __forceinline__ constexpr int WSWZ(int r) {
    return (((r) ^ ((r) >> 2)) & 7) << 2;
}

// f0 linear upsample at sample n (align_corners=True semantics, f64 pos, f32 blend)
__device__ __forceinline__ float f0_at(const float* __restrict__ row, int n) {
    double pos = (double)n * RATIO;
    double fp = floor(pos);
    int i0 = (int)fp;
    int i1 = i0 + 1; if (i1 > TT - 1) i1 = TT - 1;
    float w = (float)(pos - fp);
    return row[i0] * (1.0f - w) + row[i1] * w;
}

// ---------------- conv layers 1 & 2 as LDS-tiled register-blocked GEMM ----------------
// out[co][t] = bias[co] + sum_{ci,k} w[co][ci][k] * in[ci][t+k-PAD], then leaky-relu 0.2
// Block: 256 thr, tile 64co x 64t, thread 4co x 4t. Grid: 8B x 2cog x 32ttile = 512.
template<int K>
__global__ __launch_bounds__(256) void conv_gemm(
    const float* __restrict__ in,   // [B][128][T]
    const float* __restrict__ wgt,  // [128][128][K]
    const float* __restrict__ bias, // [128]
    float* __restrict__ out)        // [B][128][T]
{
    constexpr int PAD = K / 2;
    constexpr int TW  = 64 + K - 1;           // staged t width
    constexpr int TWP = (TW + 3) & ~3;        // padded stride
    constexpr int CC  = 16;                   // ci chunk
    constexpr int CHW = CC * K;               // weight rows per chunk
    constexpr int NCH = NMEL / CC;            // 8 chunks
    constexpr int WPT = CHW / 4;              // weight words per thread (28 / 12)

    __shared__ float Xs[CC][TWP];
    __shared__ float Ws[CHW][64];             // [ci*K+k][co ^ WSWZ(row)]

    int blk  = blockIdx.x;
    int b    = blk >> 6;
    int cog  = (blk >> 5) & 1;
    int t0   = (blk & 31) * 64;
    int cobase = cog * 64;
    int tid  = threadIdx.x;
    int tco  = tid >> 4;                      // 0..15 -> co = cobase + tco*4 ..+3
    int tt   = tid & 15;                      // 0..15 -> t  = t0 + tt*4 ..+3

    const float* inb = in + (size_t)b * NMEL * TT;

    float acc[4][4];
    #pragma unroll
    for (int j = 0; j < 4; ++j) {
        float bj = bias[cobase + tco * 4 + j];
        #pragma unroll
        for (int i = 0; i < 4; ++i) acc[j][i] = bj;
    }

    int wco = tid >> 2;                       // 0..63: co this thread stages
    int wp  = tid & 3;                        // quarter of the chunk rows

    for (int ch = 0; ch < NCH; ++ch) {
        // ---- stage X chunk [16 ci][TW t] ----
        for (int idx = tid; idx < CC * TW; idx += 256) {
            int cc = idx / TW;
            int x  = idx - cc * TW;
            int t  = t0 - PAD + x;
            Xs[cc][x] = (t >= 0 && t < TT) ? inb[(ch * CC + cc) * TT + t] : 0.0f;
        }
        // ---- stage W chunk, transposed + bank-swizzled ----
        {
            const float* wsrc = wgt + ((size_t)(cobase + wco) * NMEL + ch * CC) * K + wp * WPT;
            float tmp[WPT];
            #pragma unroll
            for (int v = 0; v < WPT / 4; ++v) {
                float4 q = ((const float4*)wsrc)[v];
                tmp[v*4+0] = q.x; tmp[v*4+1] = q.y; tmp[v*4+2] = q.z; tmp[v*4+3] = q.w;
            }
            #pragma unroll
            for (int v = 0; v < WPT; ++v) {
                int r = wp * WPT + v;
                Ws[r][wco ^ WSWZ(r)] = tmp[v];
            }
        }
        __syncthreads();

        // ---- compute ----
        #pragma unroll
        for (int cc = 0; cc < CC; ++cc) {
            float xv[4 + K - 1];
            #pragma unroll
            for (int i = 0; i < 4 + K - 1; ++i) xv[i] = Xs[cc][tt * 4 + i];
            #pragma unroll
            for (int k = 0; k < K; ++k) {
                constexpr int dummy = 0; (void)dummy;
                int r = cc * K + k;               // compile-time constant in unrolled loop
                float4 wq = *(const float4*)&Ws[r][(tco * 4) ^ WSWZ(r)];
                float wv[4] = {wq.x, wq.y, wq.z, wq.w};
                #pragma unroll
                for (int j = 0; j < 4; ++j)
                    #pragma unroll
                    for (int i = 0; i < 4; ++i)
                        acc[j][i] = fmaf(wv[j], xv[i + k], acc[j][i]);
            }
        }
        __syncthreads();
    }

    // ---- epilogue: leaky relu + float4 stores ----
    float* outb = out + ((size_t)b * NMEL + cobase + tco * 4) * TT + t0 + tt * 4;
    #pragma unroll
    for (int j = 0; j < 4; ++j) {
        float4 r;
        float v0 = acc[j][0], v1 = acc[j][1], v2 = acc[j][2], v3 = acc[j][3];
        r.x = v0 > 0.0f ? v0 : 0.2f * v0;
        r.y = v1 > 0.0f ? v1 : 0.2f * v1;
        r.z = v2 > 0.0f ? v2 : 0.2f * v2;
        r.w = v3 > 0.0f ? v3 : 0.2f * v3;
        *(float4*)(outb + (size_t)j * TT) = r;
    }
}

// ---------------- conv layer 3 (128 -> 2, clip [0,1]) ----------------
// block: 16 t x 16 ci-groups(8 ci each); grid = 8 b x 128 t-tiles = 1024 blocks
__global__ __launch_bounds__(256) void conv3_kernel(
    const float* __restrict__ in,  // [B][128][T]
    const float* __restrict__ w3,  // [2][128][3]
    const float* __restrict__ b3,  // [2]
    float* __restrict__ mags)      // [B][2][T]
{
    int b  = blockIdx.x >> 7;
    int t0 = (blockIdx.x & 127) * 16;
    int tid = threadIdx.x;
    int tt  = tid & 15;
    int cig = tid >> 4;             // 0..15
    int t = t0 + tt;
    const float* inb = in + (size_t)b * NMEL * TT;

    float a0 = 0.0f, a1 = 0.0f;
    #pragma unroll
    for (int c = 0; c < 8; ++c) {
        int ci = cig * 8 + c;
        #pragma unroll
        for (int k = 0; k < 3; ++k) {
            int t2 = t + k - 1;
            float x = (t2 >= 0 && t2 < TT) ? inb[ci * TT + t2] : 0.0f;
            a0 = fmaf(w3[ci * 3 + k], x, a0);
            a1 = fmaf(w3[384 + ci * 3 + k], x, a1);
        }
    }
    __shared__ float red[2][16][17];
    red[0][cig][tt] = a0;
    red[1][cig][tt] = a1;
    __syncthreads();
    if (tid < 32) {
        int o   = tid >> 4;
        int tt2 = tid & 15;
        float s = b3[o];
        #pragma unroll
        for (int g = 0; g < 16; ++g) s += red[o][g][tt2];
        s = fminf(fmaxf(s, 0.0f), 1.0f);
        mags[((size_t)b * 2 + o) * TT + t0 + tt2] = s;
    }
}

// ---------------- phase scan level 1: per-chunk f64 sums ----------------
__global__ __launch_bounds__(256) void chunksum_kernel(
    const float* __restrict__ f0f, double* __restrict__ sums)
{
    int b = blockIdx.x >> 7;
    int c = blockIdx.x & (NCHUNK - 1);
    const float* row = f0f + b * TT;
    int tid = threadIdx.x;
    int start = c * CHUNK + tid * 32;
    double s = 0.0;
    #pragma unroll
    for (int i = 0; i < 32; ++i)
        s += (double)f0_at(row, start + i) * INV_SR;
    __shared__ double red[256];
    red[tid] = s;
    __syncthreads();
    for (int off = 128; off > 0; off >>= 1) {
        if (tid < off) red[tid] += red[tid + off];
        __syncthreads();
    }
    if (tid == 0) sums[blockIdx.x] = red[0];
}

// ---------------- phase scan level 2: per-batch serial scan of 128 chunks ----------------
__global__ void scanoff_kernel(const double* __restrict__ sums, double* __restrict__ offs)
{
    int b = threadIdx.x;
    if (b < BATCH) {
        double run = 0.0;
        for (int c = 0; c < NCHUNK; ++c) {
            offs[b * NCHUNK + c] = run;
            run += sums[b * NCHUNK + c];
        }
    }
}

// ---------------- final fused kernel ----------------
__device__ __forceinline__ int swz(int idx) { return idx ^ ((idx >> 5) & 31); }

__global__ __launch_bounds__(256) void final_kernel(
    const float* __restrict__ f0f,
    const float* __restrict__ noise,
    const float* __restrict__ mags,
    const double* __restrict__ offs,
    float* __restrict__ out)
{
    int b = blockIdx.x >> 7;
    int c = blockIdx.x & (NCHUNK - 1);
    const float* row = f0f + b * TT;
    int tid = threadIdx.x;
    __shared__ float fracs[CHUNK];
    __shared__ double red[256];

    int chunkBase = c * CHUNK;
    int start = chunkBase + tid * 32;

    float f0v[32];
    double s = 0.0;
    #pragma unroll
    for (int i = 0; i < 32; ++i) {
        f0v[i] = f0_at(row, start + i);
        s += (double)f0v[i] * INV_SR;
    }
    red[tid] = s;
    __syncthreads();
    // Hillis-Steele inclusive scan over 256 thread sums
    for (int off = 1; off < 256; off <<= 1) {
        double v = (tid >= off) ? red[tid - off] : 0.0;
        __syncthreads();
        red[tid] += v;
        __syncthreads();
    }
    double run = offs[b * NCHUNK + c] + red[tid] - s;  // exclusive prefix for this thread

    #pragma unroll
    for (int i = 0; i < 32; ++i) {
        run += (double)f0v[i] * INV_SR;
        double fr = run - rint(run);               // phase - round(phase), half-to-even
        fracs[swz(tid * 32 + i)] = (float)fr;      // swizzled: conflict-free write & read
    }
    __syncthreads();

    const size_t BL = (size_t)BATCH * LL;
    const size_t outBase = (size_t)b * LL;
    const float* m0row = mags + (size_t)b * 2 * TT;
    const float* m1row = m0row + TT;

    #pragma unroll 4
    for (int i = 0; i < 32; ++i) {
        int idx = i * 256 + tid;                   // coalesced across lanes
        int n = chunkBase + idx;
        double pos = (double)n * RATIO;
        double fp = floor(pos);
        int i0 = (int)fp;
        int i1 = i0 + 1; if (i1 > TT - 1) i1 = TT - 1;
        float w = (float)(pos - fp);
        float f0 = row[i0] * (1.0f - w) + row[i1] * w;
        float m0 = m0row[i0] * (1.0f - w) + m0row[i1] * w;
        float m1 = m1row[i0] * (1.0f - w) + m1row[i1] * w;
        float ph = fracs[swz(idx)];
        float x = 44100.0f * ph / (f0 + 1e-8f);
        float px = 3.14159265358979323f * x;
        float comb = (x == 0.0f) ? 1.0f : (sinf(px) / px);
        float nz = noise[outBase + n];
        float ns = fminf(fmaxf(nz * m0, -1.0f), 1.0f);
        float cs = fminf(fmaxf(comb * m1, -1.0f), 1.0f);
        float sig = fminf(fmaxf(ns + cs, -1.0f), 1.0f);
        out[outBase + n]          = sig;
        out[BL + outBase + n]     = cs;
        out[2 * BL + outBase + n] = ns;
    }
}

extern "C" void kernel_launch(void* const* d_in, const int* in_sizes, int n_in,
                              void* d_out, int out_size, void* d_ws, size_t ws_size,
                              hipStream_t stream) {
    const float* mel   = (const float*)d_in[0];  // [8,128,2048]
    const float* f0f   = (const float*)d_in[1];  // [8,2048]
    const float* noise = (const float*)d_in[2];  // [8,1048576]
    const float* w1    = (const float*)d_in[3];  // [128,128,7]
    const float* b1    = (const float*)d_in[4];
    const float* w2    = (const float*)d_in[5];  // [128,128,3]
    const float* b2    = (const float*)d_in[6];
    const float* w3    = (const float*)d_in[7];  // [2,128,3]
    const float* b3    = (const float*)d_in[8];
    float* out = (float*)d_out;

    // workspace layout
    float* h1   = (float*)d_ws;                                  // 8 MB
    float* h2   = h1 + (size_t)BATCH * NMEL * TT;                // 8 MB
    float* mags = h2 + (size_t)BATCH * NMEL * TT;                // 128 KB
    double* sums = (double*)(mags + (size_t)BATCH * 2 * TT);     // 8 KB (8-byte aligned)
    double* offs = sums + BATCH * NCHUNK;                        // 8 KB

    conv_gemm<7><<<BATCH * 64, 256, 0, stream>>>(mel, w1, b1, h1);
    conv_gemm<3><<<BATCH * 64, 256, 0, stream>>>(h1, w2, b2, h2);
    conv3_kernel<<<BATCH * 128, 256, 0, stream>>>(h2, w3, b3, mags);
    chunksum_kernel<<<BATCH * NCHUNK, 256, 0, stream>>>(f0f, sums);
    scanoff_kernel<<<1, 64, 0, stream>>>(sums, offs);
    final_kernel<<<BATCH * NCHUNK, 256, 0, stream>>>(f0f, noise, mags, offs, out);
}

// Round 7
// 283.277 us; speedup vs baseline: 2.5498x; 1.0213x over previous
//
#include <hip/hip_runtime.h>
#include <math.h>

#define BATCH 8
#define NMEL 128
#define TT 2048
#define LL 1048576          // TT * 512
#define NCHUNK 128
#define CHUNK 8192          // LL / NCHUNK

static constexpr double RATIO = 2047.0 / 1048575.0;   // (T-1)/(L-1)
static constexpr double INV_SR = 1.0 / 44100.0;

// f0 linear upsample at sample n (align_corners=True semantics, f64 pos, f32 blend)
__device__ __forceinline__ float f0_at(const float* __restrict__ row, int n) {
    double pos = (double)n * RATIO;
    double fp = floor(pos);
    int i0 = (int)fp;
    int i1 = i0 + 1; if (i1 > TT - 1) i1 = TT - 1;
    float w = (float)(pos - fp);
    return row[i0] * (1.0f - w) + row[i1] * w;
}

// ---------------- weight transpose prep: w[co][m] -> wt[m][co] ----------------
__global__ __launch_bounds__(256) void wtrans_kernel(
    const float* __restrict__ w1, const float* __restrict__ w2,
    float* __restrict__ w1t, float* __restrict__ w2t)
{
    int i = blockIdx.x * 256 + threadIdx.x;
    if (i < 896 * 128) {
        int m = i >> 7, co = i & 127;
        w1t[i] = w1[co * 896 + m];
    }
    if (i < 384 * 128) {
        int m = i >> 7, co = i & 127;
        w2t[i] = w2[co * 384 + m];
    }
}

// ---------------- fused conv1+conv2+conv3 ----------------
// One block = one (b, 32-wide t tile). mel staged once; h1,h2 live in LDS.
// Thread tile: 4co x 5t (cog=tid>>3 in 0..31, tg=tid&7 in 0..7).
// H col c holds t = t0-5+c (c in 0..41; c=0,41 are zero borders).
#define XSTR 48
#define HSTR 44
__global__ __launch_bounds__(256, 2) void fused_conv(
    const float* __restrict__ mel,   // [B][128][T]
    const float* __restrict__ w1t,   // [896][128]
    const float* __restrict__ b1,    // [128]
    const float* __restrict__ w2t,   // [384][128]
    const float* __restrict__ b2,    // [128]
    const float* __restrict__ w3,    // [2][128][3]
    const float* __restrict__ b3,    // [2]
    float* __restrict__ mags)        // [B][2][T]
{
    __shared__ float Xs[NMEL * XSTR];          // mel tile [128][48], t0-8..t0+39
    __shared__ float H1[NMEL * HSTR];          // h1 tile  [128][44], cols 0..41 used
    __shared__ float H2[NMEL * HSTR];          // h2 tile  [128][44], cols 0..39 used
    __shared__ float red[2][4][32];

    int b  = blockIdx.x >> 6;
    int t0 = (blockIdx.x & 63) * 32;
    int tid = threadIdx.x;
    const float* melb = mel + (size_t)b * NMEL * TT;

    // ---- stage mel [t0-8, t0+39]: 128 rows x 12 quads (quad-aligned OOB) ----
    #pragma unroll
    for (int it = 0; it < 6; ++it) {
        int idx = tid + it * 256;              // 0..1535
        int ci = idx / 12, q = idx - ci * 12;
        int t = t0 - 8 + q * 4;
        float4 v = make_float4(0.f, 0.f, 0.f, 0.f);
        if (t >= 0 && t + 3 < TT) v = *(const float4*)(melb + ci * TT + t);
        *(float4*)(&Xs[ci * XSTR + q * 4]) = v;
    }
    // zero H1 border cols (c=0 -> t0-5, c=41 -> t0+36)
    if (tid < 128) { H1[tid * HSTR + 0] = 0.f; H1[tid * HSTR + 41] = 0.f; }
    __syncthreads();

    int cog = tid >> 3;                        // 0..31 -> co = cog*4+j
    int tg  = tid & 7;                         // 0..7  -> cols c = 1+tg*5+i
    int xbase = 1 + tg * 5;

    // ---- layer 1 (K=7): h1 cols c=1..40 (t = t0-4 .. t0+35) ----
    {
        float acc[4][5];
        #pragma unroll
        for (int j = 0; j < 4; ++j) {
            float bj = b1[cog * 4 + j];
            #pragma unroll
            for (int i = 0; i < 5; ++i) acc[j][i] = bj;
        }
        for (int ci = 0; ci < NMEL; ++ci) {
            float xv[11];
            #pragma unroll
            for (int i = 0; i < 11; ++i) xv[i] = Xs[ci * XSTR + xbase + i];
            const float* wr = w1t + (size_t)(ci * 7) * 128 + cog * 4;
            #pragma unroll
            for (int k = 0; k < 7; ++k) {
                float4 w4 = *(const float4*)(wr + k * 128);
                float wv[4] = {w4.x, w4.y, w4.z, w4.w};
                #pragma unroll
                for (int j = 0; j < 4; ++j)
                    #pragma unroll
                    for (int i = 0; i < 5; ++i)
                        acc[j][i] = fmaf(wv[j], xv[i + k], acc[j][i]);
            }
        }
        #pragma unroll
        for (int j = 0; j < 4; ++j)
            #pragma unroll
            for (int i = 0; i < 5; ++i) {
                int t = t0 - 4 + tg * 5 + i;
                float v = acc[j][i];
                v = v > 0.0f ? v : 0.2f * v;
                if (t < 0 || t >= TT) v = 0.0f;       // conv2 zero-padding
                H1[(cog * 4 + j) * HSTR + 1 + tg * 5 + i] = v;
            }
    }
    __syncthreads();

    // ---- layer 2 (K=3): h2 cols c2=0..39 (t = t0-4 .. t0+35) ----
    {
        float acc[4][5];
        #pragma unroll
        for (int j = 0; j < 4; ++j) {
            float bj = b2[cog * 4 + j];
            #pragma unroll
            for (int i = 0; i < 5; ++i) acc[j][i] = bj;
        }
        int hbase = tg * 5;                    // reads H1 cols hbase..hbase+6
        for (int ci = 0; ci < NMEL; ++ci) {
            float xv[7];
            #pragma unroll
            for (int i = 0; i < 7; ++i) xv[i] = H1[ci * HSTR + hbase + i];
            const float* wr = w2t + (size_t)(ci * 3) * 128 + cog * 4;
            #pragma unroll
            for (int k = 0; k < 3; ++k) {
                float4 w4 = *(const float4*)(wr + k * 128);
                float wv[4] = {w4.x, w4.y, w4.z, w4.w};
                #pragma unroll
                for (int j = 0; j < 4; ++j)
                    #pragma unroll
                    for (int i = 0; i < 5; ++i)
                        acc[j][i] = fmaf(wv[j], xv[i + k], acc[j][i]);
            }
        }
        #pragma unroll
        for (int j = 0; j < 4; ++j)
            #pragma unroll
            for (int i = 0; i < 5; ++i) {
                int t = t0 - 4 + tg * 5 + i;
                float v = acc[j][i];
                v = v > 0.0f ? v : 0.2f * v;
                if (t < 0 || t >= TT) v = 0.0f;       // conv3 zero-padding
                H2[(cog * 4 + j) * HSTR + tg * 5 + i] = v;
            }
    }
    __syncthreads();

    // ---- layer 3 (128 -> 2, K=3, clip [0,1]) ----
    {
        int o   = tid >> 7;                    // 0..1
        int cig = (tid >> 5) & 3;              // 0..3 (32 ci each)
        int tt  = tid & 31;                    // output t = t0+tt; H2 col tt+4
        float a = 0.0f;
        for (int cl = 0; cl < 32; ++cl) {
            int ci = cig * 32 + cl;
            #pragma unroll
            for (int k = 0; k < 3; ++k)
                a = fmaf(w3[o * 384 + ci * 3 + k], H2[ci * HSTR + tt + 3 + k], a);
        }
        red[o][cig][tt] = a;
    }
    __syncthreads();
    if (tid < 64) {
        int o = tid >> 5, tt = tid & 31;
        float s = b3[o] + red[o][0][tt] + red[o][1][tt] + red[o][2][tt] + red[o][3][tt];
        s = fminf(fmaxf(s, 0.0f), 1.0f);
        mags[((size_t)b * 2 + o) * TT + t0 + tt] = s;
    }
}

// ---------------- phase scan level 1: per-chunk f64 sums ----------------
__global__ __launch_bounds__(256) void chunksum_kernel(
    const float* __restrict__ f0f, double* __restrict__ sums)
{
    int b = blockIdx.x >> 7;
    int c = blockIdx.x & (NCHUNK - 1);
    const float* row = f0f + b * TT;
    int tid = threadIdx.x;
    int start = c * CHUNK + tid * 32;
    double s = 0.0;
    #pragma unroll
    for (int i = 0; i < 32; ++i)
        s += (double)f0_at(row, start + i) * INV_SR;
    __shared__ double red[256];
    red[tid] = s;
    __syncthreads();
    for (int off = 128; off > 0; off >>= 1) {
        if (tid < off) red[tid] += red[tid + off];
        __syncthreads();
    }
    if (tid == 0) sums[blockIdx.x] = red[0];
}

// ---------------- phase scan level 2: per-batch serial scan of 128 chunks ----------------
__global__ void scanoff_kernel(const double* __restrict__ sums, double* __restrict__ offs)
{
    int b = threadIdx.x;
    if (b < BATCH) {
        double run = 0.0;
        for (int c = 0; c < NCHUNK; ++c) {
            offs[b * NCHUNK + c] = run;
            run += sums[b * NCHUNK + c];
        }
    }
}

// ---------------- final fused kernel ----------------
__device__ __forceinline__ int swz(int idx) { return idx ^ ((idx >> 5) & 31); }

__global__ __launch_bounds__(256) void final_kernel(
    const float* __restrict__ f0f,
    const float* __restrict__ noise,
    const float* __restrict__ mags,
    const double* __restrict__ offs,
    float* __restrict__ out)
{
    int b = blockIdx.x >> 7;
    int c = blockIdx.x & (NCHUNK - 1);
    const float* row = f0f + b * TT;
    int tid = threadIdx.x;
    __shared__ float fracs[CHUNK];
    __shared__ double red[256];

    int chunkBase = c * CHUNK;
    int start = chunkBase + tid * 32;

    float f0v[32];
    double s = 0.0;
    #pragma unroll
    for (int i = 0; i < 32; ++i) {
        f0v[i] = f0_at(row, start + i);
        s += (double)f0v[i] * INV_SR;
    }
    red[tid] = s;
    __syncthreads();
    // Hillis-Steele inclusive scan over 256 thread sums
    for (int off = 1; off < 256; off <<= 1) {
        double v = (tid >= off) ? red[tid - off] : 0.0;
        __syncthreads();
        red[tid] += v;
        __syncthreads();
    }
    double run = offs[b * NCHUNK + c] + red[tid] - s;  // exclusive prefix for this thread

    #pragma unroll
    for (int i = 0; i < 32; ++i) {
        run += (double)f0v[i] * INV_SR;
        double fr = run - rint(run);               // phase - round(phase), half-to-even
        fracs[swz(tid * 32 + i)] = (float)fr;      // swizzled: conflict-free write & read
    }
    __syncthreads();

    const size_t BL = (size_t)BATCH * LL;
    const size_t outBase = (size_t)b * LL;
    const float* m0row = mags + (size_t)b * 2 * TT;
    const float* m1row = m0row + TT;

    #pragma unroll 4
    for (int i = 0; i < 32; ++i) {
        int idx = i * 256 + tid;                   // coalesced across lanes
        int n = chunkBase + idx;
        double pos = (double)n * RATIO;
        double fp = floor(pos);
        int i0 = (int)fp;
        int i1 = i0 + 1; if (i1 > TT - 1) i1 = TT - 1;
        float w = (float)(pos - fp);
        float f0 = row[i0] * (1.0f - w) + row[i1] * w;
        float m0 = m0row[i0] * (1.0f - w) + m0row[i1] * w;
        float m1 = m1row[i0] * (1.0f - w) + m1row[i1] * w;
        float ph = fracs[swz(idx)];
        float x = 44100.0f * ph / (f0 + 1e-8f);
        float px = 3.14159265358979323f * x;
        float comb = (x == 0.0f) ? 1.0f : (sinf(px) / px);
        float nz = noise[outBase + n];
        float ns = fminf(fmaxf(nz * m0, -1.0f), 1.0f);
        float cs = fminf(fmaxf(comb * m1, -1.0f), 1.0f);
        float sig = fminf(fmaxf(ns + cs, -1.0f), 1.0f);
        out[outBase + n]          = sig;
        out[BL + outBase + n]     = cs;
        out[2 * BL + outBase + n] = ns;
    }
}

extern "C" void kernel_launch(void* const* d_in, const int* in_sizes, int n_in,
                              void* d_out, int out_size, void* d_ws, size_t ws_size,
                              hipStream_t stream) {
    const float* mel   = (const float*)d_in[0];  // [8,128,2048]
    const float* f0f   = (const float*)d_in[1];  // [8,2048]
    const float* noise = (const float*)d_in[2];  // [8,1048576]
    const float* w1    = (const float*)d_in[3];  // [128,128,7]
    const float* b1    = (const float*)d_in[4];
    const float* w2    = (const float*)d_in[5];  // [128,128,3]
    const float* b2    = (const float*)d_in[6];
    const float* w3    = (const float*)d_in[7];  // [2,128,3]
    const float* b3    = (const float*)d_in[8];
    float* out = (float*)d_out;

    // workspace layout
    float* w1t  = (float*)d_ws;                      // 896*128 = 114688 f
    float* w2t  = w1t + 896 * 128;                   // 384*128 = 49152 f
    float* mags = w2t + 384 * 128;                   // 8*2*2048 = 32768 f
    double* sums = (double*)(mags + BATCH * 2 * TT); // 8B-aligned (196608 f before)
    double* offs = sums + BATCH * NCHUNK;

    wtrans_kernel<<<(896 * 128 + 255) / 256, 256, 0, stream>>>(w1, w2, w1t, w2t);
    fused_conv<<<BATCH * 64, 256, 0, stream>>>(mel, w1t, b1, w2t, b2, w3, b3, mags);
    chunksum_kernel<<<BATCH * NCHUNK, 256, 0, stream>>>(f0f, sums);
    scanoff_kernel<<<1, 64, 0, stream>>>(sums, offs);
    final_kernel<<<BATCH * NCHUNK, 256, 0, stream>>>(f0f, noise, mags, offs, out);
}

// Round 8
// 254.813 us; speedup vs baseline: 2.8346x; 1.1117x over previous
//
#include <hip/hip_runtime.h>
#include <math.h>

#define BATCH 8
#define NMEL 128
#define TT 2048
#define LL 1048576          // TT * 512
#define NCHUNK 128
#define CHUNK 8192          // LL / NCHUNK

static constexpr double RATIO = 2047.0 / 1048575.0;   // (T-1)/(L-1)
static constexpr double INV_SR = 1.0 / 44100.0;

// f0 linear upsample at sample n (align_corners=True semantics, f64 pos, f32 blend)
__device__ __forceinline__ float f0_at(const float* __restrict__ row, int n) {
    double pos = (double)n * RATIO;
    double fp = floor(pos);
    int i0 = (int)fp;
    int i1 = i0 + 1; if (i1 > TT - 1) i1 = TT - 1;
    float w = (float)(pos - fp);
    return row[i0] * (1.0f - w) + row[i1] * w;
}

// ---------------- weight transpose prep: w[co][m] -> wt[m][co] ----------------
__global__ __launch_bounds__(256) void wtrans_kernel(
    const float* __restrict__ w1, const float* __restrict__ w2,
    float* __restrict__ w1t, float* __restrict__ w2t)
{
    int i = blockIdx.x * 256 + threadIdx.x;
    if (i < 896 * 128) {
        int m = i >> 7, co = i & 127;
        w1t[i] = w1[co * 896 + m];
    }
    if (i < 384 * 128) {
        int m = i >> 7, co = i & 127;
        w2t[i] = w2[co * 384 + m];
    }
}

// ---------------- merged: fused conv (blocks 0..511) + chunksum (512..1535) ----------------
// Conv: one block = one (b, 32-wide t tile); mel staged once; H2 overlays Xs.
// LDS 48.1 KB -> 3 blocks/CU; chunksum blocks fill the 3rd slot.
#define XSTR 48
#define HSTR 44
__global__ __launch_bounds__(256, 3) void conv_chunk_kernel(
    const float* __restrict__ mel,   // [B][128][T]
    const float* __restrict__ w1t,   // [896][128]
    const float* __restrict__ b1,    // [128]
    const float* __restrict__ w2t,   // [384][128]
    const float* __restrict__ b2,    // [128]
    const float* __restrict__ w3,    // [2][128][3]
    const float* __restrict__ b3,    // [2]
    float* __restrict__ mags,        // [B][2][T]
    const float* __restrict__ f0f,   // [B][T]
    double* __restrict__ sums)       // [B*NCHUNK]
{
    __shared__ __align__(16) float smem[NMEL * XSTR + NMEL * HSTR + 256]; // 48128 B
    int tid = threadIdx.x;

    if (blockIdx.x >= 512) {
        // ================= chunksum branch =================
        int cb = blockIdx.x - 512;
        int b = cb >> 7;
        int c = cb & (NCHUNK - 1);
        const float* row = f0f + b * TT;
        int start = c * CHUNK + tid * 32;
        double s = 0.0;
        #pragma unroll
        for (int i = 0; i < 32; ++i)
            s += (double)f0_at(row, start + i) * INV_SR;
        double* dred = (double*)smem;
        dred[tid] = s;
        __syncthreads();
        for (int off = 128; off > 0; off >>= 1) {
            if (tid < off) dred[tid] += dred[tid + off];
            __syncthreads();
        }
        if (tid == 0) sums[cb] = dred[0];
        return;
    }

    // ================= conv branch =================
    float* Xs  = smem;                       // [128][48] mel tile, t0-8..t0+39
    float* H1  = smem + NMEL * XSTR;         // [128][44] h1, cols 0..41
    float* H2  = smem;                       // overlays Xs (dead after layer 1)
    float* red = smem + NMEL * XSTR + NMEL * HSTR; // [2][4][32]

    int b  = blockIdx.x >> 6;
    int t0 = (blockIdx.x & 63) * 32;
    const float* melb = mel + (size_t)b * NMEL * TT;

    // ---- stage mel: 128 rows x 12 quads (quad-aligned OOB zero-fill) ----
    #pragma unroll
    for (int it = 0; it < 6; ++it) {
        int idx = tid + it * 256;              // 0..1535
        int ci = idx / 12, q = idx - ci * 12;
        int t = t0 - 8 + q * 4;
        float4 v = make_float4(0.f, 0.f, 0.f, 0.f);
        if (t >= 0 && t + 3 < TT) v = *(const float4*)(melb + ci * TT + t);
        *(float4*)(&Xs[ci * XSTR + q * 4]) = v;
    }
    if (tid < 128) { H1[tid * HSTR + 0] = 0.f; H1[tid * HSTR + 41] = 0.f; }
    __syncthreads();

    int cog = tid >> 3;                        // 0..31 -> co = cog*4+j
    int tg  = tid & 7;                         // 0..7  -> cols c = 1+tg*5+i
    int xbase = 1 + tg * 5;

    // ---- layer 1 (K=7): h1 cols 1..40 (t = t0-4 .. t0+35) ----
    {
        float acc[4][5];
        #pragma unroll
        for (int j = 0; j < 4; ++j) {
            float bj = b1[cog * 4 + j];
            #pragma unroll
            for (int i = 0; i < 5; ++i) acc[j][i] = bj;
        }
        #pragma unroll 2
        for (int ci = 0; ci < NMEL; ++ci) {
            float xv[11];
            #pragma unroll
            for (int i = 0; i < 11; ++i) xv[i] = Xs[ci * XSTR + xbase + i];
            const float* wr = w1t + (size_t)(ci * 7) * 128 + cog * 4;
            #pragma unroll
            for (int k = 0; k < 7; ++k) {
                float4 w4 = *(const float4*)(wr + k * 128);
                float wv[4] = {w4.x, w4.y, w4.z, w4.w};
                #pragma unroll
                for (int j = 0; j < 4; ++j)
                    #pragma unroll
                    for (int i = 0; i < 5; ++i)
                        acc[j][i] = fmaf(wv[j], xv[i + k], acc[j][i]);
            }
        }
        __syncthreads();   // Xs reads done before H2 (=Xs) writes in layer 2;
                           // also orders H1 writes below vs layer-2 reads? No:
                           // H1 writes happen NOW, so a second barrier follows.
        #pragma unroll
        for (int j = 0; j < 4; ++j)
            #pragma unroll
            for (int i = 0; i < 5; ++i) {
                int t = t0 - 4 + tg * 5 + i;
                float v = acc[j][i];
                v = v > 0.0f ? v : 0.2f * v;
                if (t < 0 || t >= TT) v = 0.0f;       // conv2 zero-padding
                H1[(cog * 4 + j) * HSTR + 1 + tg * 5 + i] = v;
            }
    }
    __syncthreads();

    // ---- layer 2 (K=3): h2 cols 0..39 (t = t0-4 .. t0+35), H2 overlays Xs ----
    {
        float acc[4][5];
        #pragma unroll
        for (int j = 0; j < 4; ++j) {
            float bj = b2[cog * 4 + j];
            #pragma unroll
            for (int i = 0; i < 5; ++i) acc[j][i] = bj;
        }
        int hbase = tg * 5;                    // reads H1 cols hbase..hbase+6
        #pragma unroll 2
        for (int ci = 0; ci < NMEL; ++ci) {
            float xv[7];
            #pragma unroll
            for (int i = 0; i < 7; ++i) xv[i] = H1[ci * HSTR + hbase + i];
            const float* wr = w2t + (size_t)(ci * 3) * 128 + cog * 4;
            #pragma unroll
            for (int k = 0; k < 3; ++k) {
                float4 w4 = *(const float4*)(wr + k * 128);
                float wv[4] = {w4.x, w4.y, w4.z, w4.w};
                #pragma unroll
                for (int j = 0; j < 4; ++j)
                    #pragma unroll
                    for (int i = 0; i < 5; ++i)
                        acc[j][i] = fmaf(wv[j], xv[i + k], acc[j][i]);
            }
        }
        #pragma unroll
        for (int j = 0; j < 4; ++j)
            #pragma unroll
            for (int i = 0; i < 5; ++i) {
                int t = t0 - 4 + tg * 5 + i;
                float v = acc[j][i];
                v = v > 0.0f ? v : 0.2f * v;
                if (t < 0 || t >= TT) v = 0.0f;       // conv3 zero-padding
                H2[(cog * 4 + j) * HSTR + tg * 5 + i] = v;
            }
    }
    __syncthreads();

    // ---- layer 3 (128 -> 2, K=3, clip [0,1]) ----
    {
        int o   = tid >> 7;                    // 0..1
        int cig = (tid >> 5) & 3;              // 0..3 (32 ci each)
        int tt  = tid & 31;                    // output t = t0+tt
        float a = 0.0f;
        for (int cl = 0; cl < 32; ++cl) {
            int ci = cig * 32 + cl;
            #pragma unroll
            for (int k = 0; k < 3; ++k)
                a = fmaf(w3[o * 384 + ci * 3 + k], H2[ci * HSTR + tt + 3 + k], a);
        }
        red[(o * 4 + cig) * 32 + tt] = a;
    }
    __syncthreads();
    if (tid < 64) {
        int o = tid >> 5, tt = tid & 31;
        float s = b3[o] + red[(o * 4 + 0) * 32 + tt] + red[(o * 4 + 1) * 32 + tt]
                        + red[(o * 4 + 2) * 32 + tt] + red[(o * 4 + 3) * 32 + tt];
        s = fminf(fmaxf(s, 0.0f), 1.0f);
        mags[((size_t)b * 2 + o) * TT + t0 + tt] = s;
    }
}

// ---------------- phase scan level 2: per-batch serial scan of 128 chunks ----------------
__global__ void scanoff_kernel(const double* __restrict__ sums, double* __restrict__ offs)
{
    int b = threadIdx.x;
    if (b < BATCH) {
        double run = 0.0;
        for (int c = 0; c < NCHUNK; ++c) {
            offs[b * NCHUNK + c] = run;
            run += sums[b * NCHUNK + c];
        }
    }
}

// ---------------- final fused kernel ----------------
// fracs stored as float4 groups with XOR swizzle; conflict-free both sides.
__device__ __forceinline__ int swz4(int g) { return g ^ ((g >> 3) & 7); }

__global__ __launch_bounds__(256, 4) void final_kernel(
    const float* __restrict__ f0f,
    const float* __restrict__ noise,
    const float* __restrict__ mags,
    const double* __restrict__ offs,
    float* __restrict__ out)
{
    int b = blockIdx.x >> 7;
    int c = blockIdx.x & (NCHUNK - 1);
    const float* row = f0f + b * TT;
    int tid = threadIdx.x;
    int lane = tid & 63, wid = tid >> 6;
    __shared__ float4 fracsV[CHUNK / 4];       // 32 KB
    __shared__ double wsum[4];

    int chunkBase = c * CHUNK;
    int start = chunkBase + tid * 32;

    // ---- serial f64 phase accumulation, 32 samples/thread ----
    float f0v[32];
    double s = 0.0;
    #pragma unroll
    for (int i = 0; i < 32; ++i) {
        f0v[i] = f0_at(row, start + i);
        s += (double)f0v[i] * INV_SR;
    }
    // wave-level inclusive shfl scan + cross-wave offsets (1 barrier)
    double sinc_ = s;
    #pragma unroll
    for (int off = 1; off < 64; off <<= 1) {
        double v = __shfl_up(sinc_, (unsigned)off, 64);
        if (lane >= off) sinc_ += v;
    }
    if (lane == 63) wsum[wid] = sinc_;
    __syncthreads();
    double run = offs[b * NCHUNK + c] + (sinc_ - s);
    for (int w = 0; w < wid; ++w) run += wsum[w];

    // ---- emit phase fractions as swizzled float4 groups ----
    float fb[4];
    #pragma unroll
    for (int i = 0; i < 32; ++i) {
        run += (double)f0v[i] * INV_SR;
        double fr = run - rint(run);               // phase - round(phase)
        fb[i & 3] = (float)fr;
        if ((i & 3) == 3)
            fracsV[swz4(tid * 8 + (i >> 2))] = make_float4(fb[0], fb[1], fb[2], fb[3]);
    }
    __syncthreads();

    const size_t BL = (size_t)BATCH * LL;
    const size_t outBase = (size_t)b * LL;
    const float* m0row = mags + (size_t)b * 2 * TT;
    const float* m1row = m0row + TT;

    #pragma unroll 2
    for (int g = 0; g < 8; ++g) {
        int G = g * 256 + tid;
        int n0 = chunkBase + G * 4;
        float4 fr4 = fracsV[swz4(G)];
        const float* frp = (const float*)&fr4;
        float4 nz4 = *(const float4*)(noise + outBase + n0);
        const float* nzp = (const float*)&nz4;

        double pos0 = (double)n0 * RATIO;
        int i0a = (int)floor(pos0);
        int ib = i0a + 1 > TT - 1 ? TT - 1 : i0a + 1;
        int ic = i0a + 2 > TT - 1 ? TT - 1 : i0a + 2;
        float f0a = row[i0a],   f0b = row[ib],   f0c = row[ic];
        float m0a = m0row[i0a], m0b = m0row[ib], m0c = m0row[ic];
        float m1a = m1row[i0a], m1b = m1row[ib], m1c = m1row[ic];

        float so[4], co_[4], no_[4];
        #pragma unroll
        for (int j = 0; j < 4; ++j) {
            double pos = (double)(n0 + j) * RATIO;
            double fp = floor(pos);
            int i0 = (int)fp;
            float w = (float)(pos - fp);
            bool hi = i0 > i0a;
            float xa = hi ? f0b : f0a, xb = hi ? f0c : f0b;
            float f0 = xa * (1.0f - w) + xb * w;
            float ya = hi ? m0b : m0a, yb = hi ? m0c : m0b;
            float m0 = ya * (1.0f - w) + yb * w;
            float za = hi ? m1b : m1a, zb = hi ? m1c : m1b;
            float m1 = za * (1.0f - w) + zb * w;

            float ph = frp[j];
            float x  = 44100.0f * ph * __builtin_amdgcn_rcpf(f0 + 1e-8f);
            float px = 3.14159265358979323f * x;
            float rr = 0.5f * x;
            float rf = rr - rintf(rr);             // exact reduction to [-0.5,0.5] rev
            float sn;
            asm("v_sin_f32 %0, %1" : "=v"(sn) : "v"(rf));
            float comb = (x == 0.0f) ? 1.0f : sn * __builtin_amdgcn_rcpf(px);

            float ns = fminf(fmaxf(nzp[j] * m0, -1.0f), 1.0f);
            float cs = fminf(fmaxf(comb * m1, -1.0f), 1.0f);
            so[j] = fminf(fmaxf(ns + cs, -1.0f), 1.0f);
            co_[j] = cs; no_[j] = ns;
        }
        *(float4*)(out + outBase + n0)          = make_float4(so[0], so[1], so[2], so[3]);
        *(float4*)(out + BL + outBase + n0)     = make_float4(co_[0], co_[1], co_[2], co_[3]);
        *(float4*)(out + 2 * BL + outBase + n0) = make_float4(no_[0], no_[1], no_[2], no_[3]);
    }
}

extern "C" void kernel_launch(void* const* d_in, const int* in_sizes, int n_in,
                              void* d_out, int out_size, void* d_ws, size_t ws_size,
                              hipStream_t stream) {
    const float* mel   = (const float*)d_in[0];  // [8,128,2048]
    const float* f0f   = (const float*)d_in[1];  // [8,2048]
    const float* noise = (const float*)d_in[2];  // [8,1048576]
    const float* w1    = (const float*)d_in[3];  // [128,128,7]
    const float* b1    = (const float*)d_in[4];
    const float* w2    = (const float*)d_in[5];  // [128,128,3]
    const float* b2    = (const float*)d_in[6];
    const float* w3    = (const float*)d_in[7];  // [2,128,3]
    const float* b3    = (const float*)d_in[8];
    float* out = (float*)d_out;

    // workspace layout
    float* w1t  = (float*)d_ws;                      // 896*128
    float* w2t  = w1t + 896 * 128;                   // 384*128
    float* mags = w2t + 384 * 128;                   // 8*2*2048
    double* sums = (double*)(mags + BATCH * 2 * TT); // 8B-aligned
    double* offs = sums + BATCH * NCHUNK;

    wtrans_kernel<<<(896 * 128 + 255) / 256, 256, 0, stream>>>(w1, w2, w1t, w2t);
    conv_chunk_kernel<<<512 + BATCH * NCHUNK, 256, 0, stream>>>(
        mel, w1t, b1, w2t, b2, w3, b3, mags, f0f, sums);
    scanoff_kernel<<<1, 64, 0, stream>>>(sums, offs);
    final_kernel<<<BATCH * NCHUNK, 256, 0, stream>>>(f0f, noise, mags, offs, out);
}